// Round 2
// baseline (780.949 us; speedup 1.0000x reference)
//
#include <hip/hip_runtime.h>
#include <math.h>

#define NN 50000
#define NE 800000
#define NF 512
#define NH 128
#define NC 40
#define NCHUNK 196              // ceil(50000/256)
#define PADN (NCHUNK*256)       // 50176

// ---------------- workspace layout (bytes) ----------------
#define O_DEG1  0                     // 2*PADN ints (deg1|deg2)
#define O_CUR1  401408                // 2*PADN ints (cur1|cur2)
#define O_PART  802816                // 392 ints (+pad)
#define O_RP1   806912                // 2*PADN ints (rp_all, stride PADN)
#define O_CSC1S 1208320               // NE ints
#define O_CSC1V 4408320               // NE floats
#define O_CSC2S 7608320
#define O_CSC2V 10808320
#define O_XW    14008320              // NN*256 floats (51.2 MB)
#define O_H1    65208320              // NN*128 floats
#define O_H2    90808320              // NN*128 floats
#define O_O1    O_XW                  // reuse XW after spmm1: NN*40 floats
#define O_O2    (O_XW + 8000000)

// ---------------- CSC build ----------------
__global__ __launch_bounds__(256) void k_degree(const int* __restrict__ dst1,
                                                const int* __restrict__ dst2,
                                                int* __restrict__ deg) {
  int e = blockIdx.x * 256 + threadIdx.x;
  if (e < NE) {
    atomicAdd(&deg[dst1[e]], 1);
    atomicAdd(&deg[PADN + dst2[e]], 1);
  }
}

__global__ __launch_bounds__(256) void k_chunk_sum(const int* __restrict__ deg,
                                                   int* __restrict__ part) {
  __shared__ int sm[256];
  sm[threadIdx.x] = deg[blockIdx.x * 256 + threadIdx.x];
  __syncthreads();
  for (int off = 128; off > 0; off >>= 1) {
    if (threadIdx.x < off) sm[threadIdx.x] += sm[threadIdx.x + off];
    __syncthreads();
  }
  if (threadIdx.x == 0) part[blockIdx.x] = sm[0];
}

// segmented exclusive scan of the 2*NCHUNK chunk sums (segments of NCHUNK)
__global__ __launch_bounds__(512) void k_scan_part(int* __restrict__ part) {
  __shared__ int s[512];
  int t = threadIdx.x;
  int seg = t >> 8, i = t & 255;
  int active = (i < NCHUNK);
  int v = active ? part[seg * NCHUNK + i] : 0;
  s[t] = v;
  __syncthreads();
  for (int off = 1; off < 256; off <<= 1) {
    int u = (i >= off) ? s[seg * 256 + i - off] : 0;
    __syncthreads();
    s[t] += u;
    __syncthreads();
  }
  if (active) part[seg * NCHUNK + i] = s[t] - v;  // exclusive
}

__global__ __launch_bounds__(256) void k_chunk_scan(const int* __restrict__ deg,
                                                    const int* __restrict__ part,
                                                    int* __restrict__ rp_all) {
  __shared__ int s[256];
  int b = blockIdx.x;                 // 0..391
  int t = threadIdx.x;
  int v = deg[b * 256 + t];
  s[t] = v;
  __syncthreads();
  for (int off = 1; off < 256; off <<= 1) {
    int u = (t >= off) ? s[t - off] : 0;
    __syncthreads();
    s[t] += u;
    __syncthreads();
  }
  int seg = (b >= NCHUNK) ? 1 : 0;
  int lb = b - seg * NCHUNK;
  int lidx = lb * 256 + t;
  int excl = part[b] + s[t] - v;
  if (lidx <= NN) rp_all[seg * PADN + lidx] = excl;
}

__global__ __launch_bounds__(256) void k_scatter(const int* __restrict__ src,
                                                 const int* __restrict__ dst,
                                                 const float* __restrict__ val,
                                                 const int* __restrict__ rp,
                                                 int* __restrict__ cur,
                                                 int* __restrict__ csrc,
                                                 float* __restrict__ cval) {
  int e = blockIdx.x * 256 + threadIdx.x;
  if (e < NE) {
    int d = dst[e];
    int p = atomicAdd(&cur[d], 1);
    int idx = rp[d] + p;
    csrc[idx] = src[e];
    cval[idx] = val[e];
  }
}

// ---------------- GEMM1: XW[N,256] = x[N,512] @ [W1|W3] ----------------
// 64x64 block tile, 4x4 per-thread register tile, K staged 32 at a time.
// xs[64][36]: pad 36 -> 16-addr b128 reads are 2-way (free, m136).
// ws[32][68]: pad 68 -> 4-addr broadcast reads, 2-way (free).
__global__ __launch_bounds__(256) void k_gemm1(const float* __restrict__ x,
                                               const float* __restrict__ W1,
                                               const float* __restrict__ W3,
                                               float* __restrict__ XW) {
  __shared__ float xs[64 * 36];       // 9216 B
  __shared__ float ws[32 * 68];       // 8704 B
  int t = threadIdx.x;
  int m0 = blockIdx.x * 64;
  int cb4 = blockIdx.y;               // 0..3 : 64-col slab of XW's 256
  const float* W = (cb4 < 2) ? W1 : W3;
  int colbase = (cb4 & 1) * 64;

  int mt = t & 15;                    // row group: rows mt + 16*i
  int nt = t >> 4;                    // col group: cols 4*nt + j

  float acc[4][4];
#pragma unroll
  for (int i = 0; i < 4; i++)
#pragma unroll
    for (int j = 0; j < 4; j++) acc[i][j] = 0.f;

  // staging indices
  int xc = t & 7;                     // float4 index along k (k = 4*xc..4*xc+3)
  int xr = t >> 3;                    // row 0..31 (pass adds 32)
  int wn4 = t & 15;                   // float4 index along n (n = 4*wn4)
  int wk = t >> 4;                    // k row 0..15 (pass adds 16)

  for (int kt = 0; kt < 16; kt++) {
    int k0 = kt * 32;
    // stage x tile [64][32]
#pragma unroll
    for (int p = 0; p < 2; p++) {
      int row = xr + 32 * p;
      float4 v;
      if (m0 + row < NN)
        v = *(const float4*)(x + (size_t)(m0 + row) * NF + k0 + 4 * xc);
      else
        v = make_float4(0.f, 0.f, 0.f, 0.f);
      *(float4*)(xs + row * 36 + 4 * xc) = v;
    }
    // stage W tile [32][64]
#pragma unroll
    for (int p = 0; p < 2; p++) {
      int k = wk + 16 * p;
      float4 v = *(const float4*)(W + (size_t)(k0 + k) * NH + colbase + 4 * wn4);
      *(float4*)(ws + k * 68 + 4 * wn4) = v;
    }
    __syncthreads();

#pragma unroll
    for (int k4 = 0; k4 < 8; k4++) {
      float4 xv[4], wv[4];
#pragma unroll
      for (int i = 0; i < 4; i++)
        xv[i] = *(const float4*)(xs + (mt + 16 * i) * 36 + 4 * k4);
#pragma unroll
      for (int kk = 0; kk < 4; kk++)
        wv[kk] = *(const float4*)(ws + (4 * k4 + kk) * 68 + 4 * nt);
#pragma unroll
      for (int i = 0; i < 4; i++) {
        acc[i][0] = fmaf(xv[i].x, wv[0].x, acc[i][0]);
        acc[i][1] = fmaf(xv[i].x, wv[0].y, acc[i][1]);
        acc[i][2] = fmaf(xv[i].x, wv[0].z, acc[i][2]);
        acc[i][3] = fmaf(xv[i].x, wv[0].w, acc[i][3]);
        acc[i][0] = fmaf(xv[i].y, wv[1].x, acc[i][0]);
        acc[i][1] = fmaf(xv[i].y, wv[1].y, acc[i][1]);
        acc[i][2] = fmaf(xv[i].y, wv[1].z, acc[i][2]);
        acc[i][3] = fmaf(xv[i].y, wv[1].w, acc[i][3]);
        acc[i][0] = fmaf(xv[i].z, wv[2].x, acc[i][0]);
        acc[i][1] = fmaf(xv[i].z, wv[2].y, acc[i][1]);
        acc[i][2] = fmaf(xv[i].z, wv[2].z, acc[i][2]);
        acc[i][3] = fmaf(xv[i].z, wv[2].w, acc[i][3]);
        acc[i][0] = fmaf(xv[i].w, wv[3].x, acc[i][0]);
        acc[i][1] = fmaf(xv[i].w, wv[3].y, acc[i][1]);
        acc[i][2] = fmaf(xv[i].w, wv[3].z, acc[i][2]);
        acc[i][3] = fmaf(xv[i].w, wv[3].w, acc[i][3]);
      }
    }
    __syncthreads();
  }

  // epilogue: float4 store per row
#pragma unroll
  for (int i = 0; i < 4; i++) {
    int row = m0 + mt + 16 * i;
    if (row < NN) {
      float4 v = make_float4(acc[i][0], acc[i][1], acc[i][2], acc[i][3]);
      *(float4*)(XW + (size_t)row * 256 + cb4 * 64 + 4 * nt) = v;
    }
  }
}

// ---------------- SpMM layer1 (F=128) + bias + relu ----------------
__global__ __launch_bounds__(256) void k_spmm_h(const float* __restrict__ XW,
    const int* __restrict__ rp_all,
    const int* __restrict__ cs1, const float* __restrict__ cv1,
    const int* __restrict__ cs2, const float* __restrict__ cv2,
    const float* __restrict__ b1, const float* __restrict__ b3,
    float* __restrict__ h1, float* __restrict__ h2) {
  int tower = blockIdx.y;
  const int* rp = rp_all + tower * PADN;
  const int* csrc = tower ? cs2 : cs1;
  const float* cval = tower ? cv2 : cv1;
  const float* bias = tower ? b3 : b1;
  float* hout = tower ? h2 : h1;
  int cb = tower * NH;
  int wid = threadIdx.x >> 6, lane = threadIdx.x & 63;
  int d = blockIdx.x * 4 + wid;   // grid.x = 12500 exactly
  int beg = rp[d], end = rp[d + 1];
  float a0 = 0.f, a1 = 0.f;
  int j = beg;
  for (; j + 1 < end; j += 2) {
    int s0 = csrc[j], s1 = csrc[j + 1];
    float v0 = cval[j], v1 = cval[j + 1];
    const float* r0 = XW + (size_t)s0 * 256 + cb;
    const float* r1 = XW + (size_t)s1 * 256 + cb;
    float x00 = r0[lane], x01 = r0[lane + 64];
    float x10 = r1[lane], x11 = r1[lane + 64];
    a0 = fmaf(v0, x00, a0); a1 = fmaf(v0, x01, a1);
    a0 = fmaf(v1, x10, a0); a1 = fmaf(v1, x11, a1);
  }
  if (j < end) {
    int s0 = csrc[j]; float v0 = cval[j];
    const float* r0 = XW + (size_t)s0 * 256 + cb;
    a0 = fmaf(v0, r0[lane], a0);
    a1 = fmaf(v0, r0[lane + 64], a1);
  }
  float o0 = fmaxf(a0 + bias[lane], 0.f);
  float o1 = fmaxf(a1 + bias[lane + 64], 0.f);
  hout[(size_t)d * NH + lane] = o0;
  hout[(size_t)d * NH + lane + 64] = o1;
}

// ---------------- GEMM2: O[N,40] = h[N,128] @ W (no bias here) ----------------
#define G2R 32
__global__ __launch_bounds__(256) void k_gemm2(const float* __restrict__ h1,
                                               const float* __restrict__ h2,
                                               const float* __restrict__ W2,
                                               const float* __restrict__ W4,
                                               float* __restrict__ O1,
                                               float* __restrict__ O2) {
  int tower = blockIdx.y;
  const float* h = tower ? h2 : h1;
  const float* W = tower ? W4 : W2;
  float* O = tower ? O2 : O1;
  __shared__ float hs[G2R * 132];     // padded stride 132
  __shared__ float Ws[NH * NC];       // 20 KB
  int t = threadIdx.x;
  int r0 = blockIdx.x * G2R;
  for (int i = 0; i < 5; i++)
    ((float4*)Ws)[i * 256 + t] = ((const float4*)W)[i * 256 + t];
  for (int i = 0; i < 4; i++) {
    int f4 = i * 256 + t;
    int row = f4 >> 5;
    int c4 = f4 & 31;
    float4 v;
    if (r0 + row < NN) v = ((const float4*)(h + (size_t)(r0 + row) * NH))[c4];
    else v = make_float4(0.f, 0.f, 0.f, 0.f);
    ((float4*)(hs + row * 132))[c4] = v;
  }
  __syncthreads();
  int r = t >> 3, cj = t & 7;
  float acc[5] = {0.f, 0.f, 0.f, 0.f, 0.f};
  for (int k4 = 0; k4 < NH / 4; k4++) {
    float4 hv = ((const float4*)(hs + r * 132))[k4];
    int k = k4 * 4;
#pragma unroll
    for (int j = 0; j < 5; j++) acc[j] = fmaf(hv.x, Ws[(k + 0) * NC + cj * 5 + j], acc[j]);
#pragma unroll
    for (int j = 0; j < 5; j++) acc[j] = fmaf(hv.y, Ws[(k + 1) * NC + cj * 5 + j], acc[j]);
#pragma unroll
    for (int j = 0; j < 5; j++) acc[j] = fmaf(hv.z, Ws[(k + 2) * NC + cj * 5 + j], acc[j]);
#pragma unroll
    for (int j = 0; j < 5; j++) acc[j] = fmaf(hv.w, Ws[(k + 3) * NC + cj * 5 + j], acc[j]);
  }
  if (r0 + r < NN) {
    for (int j = 0; j < 5; j++)
      O[(size_t)(r0 + r) * NC + cj * 5 + j] = acc[j];
  }
}

// ------- fused: spmm2 (both towers) + bias + gate GEMV + sigmoid + log_softmax -------
__global__ __launch_bounds__(256) void k_out(const float* __restrict__ O1g,
    const float* __restrict__ O2g,
    const int* __restrict__ rp_all,
    const int* __restrict__ cs1, const float* __restrict__ cv1,
    const int* __restrict__ cs2, const float* __restrict__ cv2,
    const float* __restrict__ b2, const float* __restrict__ b4,
    const float* __restrict__ Wl, const float* __restrict__ bl,
    float* __restrict__ out) {
  __shared__ float Wls[80 * NC];      // 12.8 KB
  __shared__ float cat[4][80];
  int t = threadIdx.x;
  for (int i = 0; i < 4; i++) {
    int idx = i * 256 + t;
    if (idx < 800) ((float4*)Wls)[idx] = ((const float4*)Wl)[idx];
  }
  __syncthreads();
  int wid = t >> 6, lane = t & 63;
  int d = blockIdx.x * 4 + wid;       // grid.x = 12500 exactly
  float o1 = 0.f, o2 = 0.f;
  if (lane < NC) {
    int beg = rp_all[d], end = rp_all[d + 1];
    int j = beg;
    for (; j + 1 < end; j += 2) {
      int s0 = cs1[j], s1 = cs1[j + 1];
      float v0 = cv1[j], v1 = cv1[j + 1];
      o1 = fmaf(v0, O1g[(size_t)s0 * NC + lane], o1);
      o1 = fmaf(v1, O1g[(size_t)s1 * NC + lane], o1);
    }
    if (j < end) o1 = fmaf(cv1[j], O1g[(size_t)cs1[j] * NC + lane], o1);
    beg = rp_all[PADN + d]; end = rp_all[PADN + d + 1];
    j = beg;
    for (; j + 1 < end; j += 2) {
      int s0 = cs2[j], s1 = cs2[j + 1];
      float v0 = cv2[j], v1 = cv2[j + 1];
      o2 = fmaf(v0, O2g[(size_t)s0 * NC + lane], o2);
      o2 = fmaf(v1, O2g[(size_t)s1 * NC + lane], o2);
    }
    if (j < end) o2 = fmaf(cv2[j], O2g[(size_t)cs2[j] * NC + lane], o2);
    o1 += b2[lane];
    o2 += b4[lane];
    cat[wid][lane] = o1;
    cat[wid][NC + lane] = o2;
  }
  __syncthreads();
  float g = 0.f;
  if (lane < NC) {
    for (int k = 0; k < 2 * NC; k++)
      g = fmaf(cat[wid][k], Wls[k * NC + lane], g);
    g = 1.f / (1.f + __expf(-(g + bl[lane])));
  }
  float val = (lane < NC) ? (g * o1 + (1.f - g) * o2) : -INFINITY;
  float m = val;
#pragma unroll
  for (int off = 32; off > 0; off >>= 1) m = fmaxf(m, __shfl_xor(m, off));
  float ex = (lane < NC) ? __expf(val - m) : 0.f;
  float s = ex;
#pragma unroll
  for (int off = 32; off > 0; off >>= 1) s += __shfl_xor(s, off);
  if (lane < NC) out[(size_t)d * NC + lane] = val - m - __logf(s);
}

// ---------------- host ----------------
extern "C" void kernel_launch(void* const* d_in, const int* in_sizes, int n_in,
                              void* d_out, int out_size, void* d_ws, size_t ws_size,
                              hipStream_t stream) {
  const float* x   = (const float*)d_in[0];
  const int*   ei1 = (const int*)d_in[1];
  const float* ev1 = (const float*)d_in[2];
  const int*   ei2 = (const int*)d_in[3];
  const float* ev2 = (const float*)d_in[4];
  const float* W1  = (const float*)d_in[5];
  const float* b1  = (const float*)d_in[6];
  const float* W2  = (const float*)d_in[7];
  const float* b2  = (const float*)d_in[8];
  const float* W3  = (const float*)d_in[9];
  const float* b3  = (const float*)d_in[10];
  const float* W4  = (const float*)d_in[11];
  const float* b4  = (const float*)d_in[12];
  const float* Wl  = (const float*)d_in[13];
  const float* bl  = (const float*)d_in[14];
  float* out = (float*)d_out;
  char* ws = (char*)d_ws;

  int*   deg   = (int*)(ws + O_DEG1);
  int*   cur1  = (int*)(ws + O_CUR1);
  int*   cur2  = (int*)(ws + O_CUR1 + PADN * 4);
  int*   part  = (int*)(ws + O_PART);
  int*   rp    = (int*)(ws + O_RP1);       // rp_all, stride PADN
  int*   cs1   = (int*)(ws + O_CSC1S);
  float* cv1   = (float*)(ws + O_CSC1V);
  int*   cs2   = (int*)(ws + O_CSC2S);
  float* cv2   = (float*)(ws + O_CSC2V);
  float* XW    = (float*)(ws + O_XW);
  float* h1    = (float*)(ws + O_H1);
  float* h2    = (float*)(ws + O_H2);
  float* O1    = (float*)(ws + O_O1);
  float* O2    = (float*)(ws + O_O2);

  const int* src1 = ei1;
  const int* dst1 = ei1 + NE;
  const int* src2 = ei2;
  const int* dst2 = ei2 + NE;

  // zero deg1|deg2|cur1|cur2 (contiguous)
  hipMemsetAsync(ws + O_DEG1, 0, (size_t)4 * PADN * 4, stream);

  dim3 bs(256);
  k_degree<<<dim3((NE + 255) / 256), bs, 0, stream>>>(dst1, dst2, deg);
  k_chunk_sum<<<dim3(2 * NCHUNK), bs, 0, stream>>>(deg, part);
  k_scan_part<<<dim3(1), dim3(512), 0, stream>>>(part);
  k_chunk_scan<<<dim3(2 * NCHUNK), bs, 0, stream>>>(deg, part, rp);
  k_scatter<<<dim3((NE + 255) / 256), bs, 0, stream>>>(src1, dst1, ev1, rp, cur1, cs1, cv1);
  k_scatter<<<dim3((NE + 255) / 256), bs, 0, stream>>>(src2, dst2, ev2, rp + PADN, cur2, cs2, cv2);

  k_gemm1<<<dim3((NN + 63) / 64, 4), bs, 0, stream>>>(x, W1, W3, XW);
  k_spmm_h<<<dim3(NN / 4, 2), bs, 0, stream>>>(XW, rp, cs1, cv1, cs2, cv2, b1, b3, h1, h2);
  k_gemm2<<<dim3((NN + G2R - 1) / G2R, 2), bs, 0, stream>>>(h1, h2, W2, W4, O1, O2);
  k_out<<<dim3(NN / 4), bs, 0, stream>>>(O1, O2, rp, cs1, cv1, cs2, cv2, b2, b4, Wl, bl, out);
}

// Round 5
// 603.348 us; speedup vs baseline: 1.2944x; 1.2944x over previous
//
#include <hip/hip_runtime.h>
#include <math.h>

#define NN 50000
#define NE 800000
#define NF 512
#define NH 128
#define NC 40
#define NCHUNK 196              // ceil(50000/256)
#define PADN (NCHUNK*256)       // 50176
#define MPAD 50048              // 391*128

typedef __bf16 bf16x8 __attribute__((ext_vector_type(8)));
typedef __bf16 bf16x2 __attribute__((ext_vector_type(2)));
typedef float f32x4 __attribute__((ext_vector_type(4)));

// ---------------- workspace layout (bytes) ----------------
#define O_DEG   0                     // 2*PADN ints (deg1|deg2)
#define O_CUR   401408                // 2*PADN ints (cur1|cur2)
#define O_PART  802816                // 392 ints (+pad)
#define O_RP    806912                // 2*PADN ints (rp_all, stride PADN)
#define O_E1    1208320               // NE int2 (src, val-bits)
#define O_E2    7608320               // NE int2
#define O_WBT   14008320              // 256*512 bf16
#define O_XW    14270464              // MPAD*256 bf16
#define O_H1    39895040              // MPAD*128 bf16
#define O_H2    52707328              // MPAD*128 bf16
#define O_O1    65519616              // MPAD*40 bf16
#define O_O2    69523456              // MPAD*40 bf16  (end 73527296)

// ---------------- CSC build ----------------
__global__ __launch_bounds__(256) void k_degree(const int* __restrict__ dst1,
                                                const int* __restrict__ dst2,
                                                int* __restrict__ deg) {
  int e = blockIdx.x * 256 + threadIdx.x;
  if (e < NE) {
    atomicAdd(&deg[dst1[e]], 1);
    atomicAdd(&deg[PADN + dst2[e]], 1);
  }
}

__global__ __launch_bounds__(256) void k_chunk_sum(const int* __restrict__ deg,
                                                   int* __restrict__ part) {
  __shared__ int sm[256];
  sm[threadIdx.x] = deg[blockIdx.x * 256 + threadIdx.x];
  __syncthreads();
  for (int off = 128; off > 0; off >>= 1) {
    if (threadIdx.x < off) sm[threadIdx.x] += sm[threadIdx.x + off];
    __syncthreads();
  }
  if (threadIdx.x == 0) part[blockIdx.x] = sm[0];
}

__global__ __launch_bounds__(512) void k_scan_part(int* __restrict__ part) {
  __shared__ int s[512];
  int t = threadIdx.x;
  int seg = t >> 8, i = t & 255;
  int active = (i < NCHUNK);
  int v = active ? part[seg * NCHUNK + i] : 0;
  s[t] = v;
  __syncthreads();
  for (int off = 1; off < 256; off <<= 1) {
    int u = (i >= off) ? s[seg * 256 + i - off] : 0;
    __syncthreads();
    s[t] += u;
    __syncthreads();
  }
  if (active) part[seg * NCHUNK + i] = s[t] - v;  // exclusive
}

__global__ __launch_bounds__(256) void k_chunk_scan(const int* __restrict__ deg,
                                                    const int* __restrict__ part,
                                                    int* __restrict__ rp_all) {
  __shared__ int s[256];
  int b = blockIdx.x;                 // 0..391
  int t = threadIdx.x;
  int v = deg[b * 256 + t];
  s[t] = v;
  __syncthreads();
  for (int off = 1; off < 256; off <<= 1) {
    int u = (t >= off) ? s[t - off] : 0;
    __syncthreads();
    s[t] += u;
    __syncthreads();
  }
  int seg = (b >= NCHUNK) ? 1 : 0;
  int lb = b - seg * NCHUNK;
  int lidx = lb * 256 + t;
  int excl = part[b] + s[t] - v;
  if (lidx <= NN) rp_all[seg * PADN + lidx] = excl;
}

__global__ __launch_bounds__(256) void k_scatter(const int* __restrict__ src,
                                                 const int* __restrict__ dst,
                                                 const float* __restrict__ val,
                                                 const int* __restrict__ rp,
                                                 int* __restrict__ cur,
                                                 int2* __restrict__ epack) {
  int e = blockIdx.x * 256 + threadIdx.x;
  if (e < NE) {
    int d = dst[e];
    int p = atomicAdd(&cur[d], 1);
    epack[rp[d] + p] = make_int2(src[e], __float_as_int(val[e]));
  }
}

// ---------------- W -> bf16 transposed [256 n][512 k] ----------------
__global__ __launch_bounds__(256) void k_wcvt(const float* __restrict__ W1,
                                              const float* __restrict__ W3,
                                              __bf16* __restrict__ Wbt) {
  int k = blockIdx.x;                 // 0..511
  int t = threadIdx.x;                // 0..255 = output col
  float v = (t < 128) ? W1[k * 128 + t] : W3[k * 128 + (t - 128)];
  Wbt[(size_t)t * 512 + k] = (__bf16)v;
}

// ---------------- GEMM1 (MFMA): XW[MPAD,256]bf16 = x[N,512] @ [W1|W3] ----------------
// block tile 128x256, 8 waves (2M x 4N), wave tile 64x64, BK=64.
// LDS: As[128][64]bf16 (16KB) + Bs[256][64]bf16 (32KB), XOR-swizzled (T2/G4).
__global__ __launch_bounds__(512) void k_gemm1(const float* __restrict__ x,
                                               const __bf16* __restrict__ Wbt,
                                               __bf16* __restrict__ XWb) {
  __shared__ __align__(16) char smem[49152];
  const int t = threadIdx.x;
  const int m0 = blockIdx.x * 128;
  const int lane = t & 63, wid = t >> 6;
  const int wm = wid >> 2, wn = wid & 3;
  const int lr = lane & 15, lk = lane >> 4;
  const int sw = (lr & 7) << 4;

  int arow[4], brow[4];
#pragma unroll
  for (int mi = 0; mi < 4; mi++) arow[mi] = (wm * 64 + mi * 16 + lr) * 128;
#pragma unroll
  for (int ni = 0; ni < 4; ni++) brow[ni] = 16384 + (wn * 64 + ni * 16 + lr) * 128;

  f32x4 acc[4][4];
#pragma unroll
  for (int mi = 0; mi < 4; mi++)
#pragma unroll
    for (int ni = 0; ni < 4; ni++) acc[mi][ni] = (f32x4){0.f, 0.f, 0.f, 0.f};

  for (int kt = 0; kt < 8; ++kt) {
    int k0 = kt * 64;
    // stage A: 128 rows x 64 k, bf16, 1024 16B-chunks (2/thread), fp32->bf16 cvt
#pragma unroll
    for (int i = 0; i < 2; ++i) {
      int c = t + i * 512;
      int r = c >> 3, kq = c & 7;
      int grow = m0 + r;
      float4 f0, f1;
      if (grow < NN) {
        const float* p = x + (size_t)grow * NF + k0 + kq * 8;
        f0 = *(const float4*)p;
        f1 = *(const float4*)(p + 4);
      } else {
        f0 = make_float4(0.f, 0.f, 0.f, 0.f);
        f1 = f0;
      }
      bf16x8 ch;
      ch[0] = (__bf16)f0.x; ch[1] = (__bf16)f0.y; ch[2] = (__bf16)f0.z; ch[3] = (__bf16)f0.w;
      ch[4] = (__bf16)f1.x; ch[5] = (__bf16)f1.y; ch[6] = (__bf16)f1.z; ch[7] = (__bf16)f1.w;
      int addr = (r * 128 + kq * 16) ^ ((r & 7) << 4);
      *(bf16x8*)(smem + addr) = ch;
    }
    // stage B: 256 n-rows x 64 k, 2048 chunks (4/thread), already bf16
#pragma unroll
    for (int i = 0; i < 4; ++i) {
      int c = t + i * 512;
      int n = c >> 3, kq = c & 7;
      bf16x8 ch = *(const bf16x8*)(Wbt + (size_t)n * 512 + k0 + kq * 8);
      int addr = 16384 + ((n * 128 + kq * 16) ^ ((n & 7) << 4));
      *(bf16x8*)(smem + addr) = ch;
    }
    __syncthreads();

#pragma unroll
    for (int kb = 0; kb < 2; ++kb) {
      int kbyte = (kb * 64 + lk * 16) ^ sw;
      bf16x8 af[4], bfr[4];
#pragma unroll
      for (int mi = 0; mi < 4; mi++) af[mi] = *(const bf16x8*)(smem + arow[mi] + kbyte);
#pragma unroll
      for (int ni = 0; ni < 4; ni++) bfr[ni] = *(const bf16x8*)(smem + brow[ni] + kbyte);
#pragma unroll
      for (int mi = 0; mi < 4; mi++)
#pragma unroll
        for (int ni = 0; ni < 4; ni++)
          acc[mi][ni] = __builtin_amdgcn_mfma_f32_16x16x32_bf16(af[mi], bfr[ni], acc[mi][ni], 0, 0, 0);
    }
    __syncthreads();
  }

  // epilogue: C frag row=(lane>>4)*4+reg, col=lane&15
#pragma unroll
  for (int mi = 0; mi < 4; mi++) {
#pragma unroll
    for (int ni = 0; ni < 4; ni++) {
#pragma unroll
      for (int reg = 0; reg < 4; reg++) {
        int row = m0 + wm * 64 + mi * 16 + lk * 4 + reg;
        int col = wn * 64 + ni * 16 + lr;
        XWb[(size_t)row * 256 + col] = (__bf16)acc[mi][ni][reg];
      }
    }
  }
}

// ---------------- SpMM layer1 (F=128 bf16) + bias + relu -> h bf16 ----------------
__global__ __launch_bounds__(256) void k_spmm_h(const __bf16* __restrict__ XWb,
    const int* __restrict__ rp_all,
    const int2* __restrict__ e1, const int2* __restrict__ e2,
    const float* __restrict__ b1, const float* __restrict__ b3,
    __bf16* __restrict__ h1, __bf16* __restrict__ h2) {
  int tower = blockIdx.y;
  const int* rp = rp_all + tower * PADN;
  const int2* ed = tower ? e2 : e1;
  const float* bias = tower ? b3 : b1;
  __bf16* hout = tower ? h2 : h1;
  int wid = threadIdx.x >> 6, lane = threadIdx.x & 63;
  int d = blockIdx.x * 4 + wid;       // grid.x = 12500 exactly
  int beg = rp[d], end = rp[d + 1];
  float a0 = 0.f, a1 = 0.f;
  const __bf16* base = XWb + tower * 128 + 2 * lane;
  int j = beg;
  for (; j + 1 < end; j += 2) {
    int2 ea = ed[j], eb = ed[j + 1];
    float va = __int_as_float(ea.y), vb = __int_as_float(eb.y);
    bf16x2 xa = *(const bf16x2*)(base + (size_t)ea.x * 256);
    bf16x2 xb = *(const bf16x2*)(base + (size_t)eb.x * 256);
    a0 = fmaf(va, (float)xa[0], a0); a1 = fmaf(va, (float)xa[1], a1);
    a0 = fmaf(vb, (float)xb[0], a0); a1 = fmaf(vb, (float)xb[1], a1);
  }
  if (j < end) {
    int2 ea = ed[j];
    float va = __int_as_float(ea.y);
    bf16x2 xa = *(const bf16x2*)(base + (size_t)ea.x * 256);
    a0 = fmaf(va, (float)xa[0], a0); a1 = fmaf(va, (float)xa[1], a1);
  }
  float o0 = fmaxf(a0 + bias[2 * lane], 0.f);
  float o1 = fmaxf(a1 + bias[2 * lane + 1], 0.f);
  bf16x2 hv; hv[0] = (__bf16)o0; hv[1] = (__bf16)o1;
  *(bf16x2*)(hout + (size_t)d * NH + 2 * lane) = hv;
}

// ---------------- GEMM2: O[N,40]bf16 = h[N,128]bf16 @ W (fp32 compute) ----------------
#define G2R 32
__global__ __launch_bounds__(256) void k_gemm2(const __bf16* __restrict__ h1,
                                               const __bf16* __restrict__ h2,
                                               const float* __restrict__ W2,
                                               const float* __restrict__ W4,
                                               __bf16* __restrict__ O1,
                                               __bf16* __restrict__ O2) {
  int tower = blockIdx.y;
  const __bf16* h = tower ? h2 : h1;
  const float* W = tower ? W4 : W2;
  __bf16* O = tower ? O2 : O1;
  __shared__ float hs[G2R * 132];     // padded stride 132
  __shared__ float Ws[NH * NC];       // 20 KB
  int t = threadIdx.x;
  int r0 = blockIdx.x * G2R;
  for (int i = 0; i < 5; i++)
    ((float4*)Ws)[i * 256 + t] = ((const float4*)W)[i * 256 + t];
  // stage h: 32 rows x 128 bf16 = 512 16B-chunks, 2/thread, cvt to fp32
#pragma unroll
  for (int i = 0; i < 2; i++) {
    int c = i * 256 + t;
    int row = c >> 4, c8 = c & 15;
    bf16x8 raw;
    if (r0 + row < NN) raw = *(const bf16x8*)(h + (size_t)(r0 + row) * NH + c8 * 8);
    else { bf16x8 z = {}; raw = z; }
    float4 lo = make_float4((float)raw[0], (float)raw[1], (float)raw[2], (float)raw[3]);
    float4 hi = make_float4((float)raw[4], (float)raw[5], (float)raw[6], (float)raw[7]);
    *(float4*)(hs + row * 132 + c8 * 8) = lo;
    *(float4*)(hs + row * 132 + c8 * 8 + 4) = hi;
  }
  __syncthreads();
  int r = t >> 3, cj = t & 7;
  float acc[5] = {0.f, 0.f, 0.f, 0.f, 0.f};
  for (int k4 = 0; k4 < NH / 4; k4++) {
    float4 hv = ((const float4*)(hs + r * 132))[k4];
    int k = k4 * 4;
#pragma unroll
    for (int j = 0; j < 5; j++) acc[j] = fmaf(hv.x, Ws[(k + 0) * NC + cj * 5 + j], acc[j]);
#pragma unroll
    for (int j = 0; j < 5; j++) acc[j] = fmaf(hv.y, Ws[(k + 1) * NC + cj * 5 + j], acc[j]);
#pragma unroll
    for (int j = 0; j < 5; j++) acc[j] = fmaf(hv.z, Ws[(k + 2) * NC + cj * 5 + j], acc[j]);
#pragma unroll
    for (int j = 0; j < 5; j++) acc[j] = fmaf(hv.w, Ws[(k + 3) * NC + cj * 5 + j], acc[j]);
  }
  if (r0 + r < NN) {
#pragma unroll
    for (int j = 0; j < 5; j++)
      O[(size_t)(r0 + r) * NC + cj * 5 + j] = (__bf16)acc[j];
  }
}

// ------- fused: spmm2 (both towers, bf16 gather) + bias + gate + log_softmax -------
__global__ __launch_bounds__(256) void k_out(const __bf16* __restrict__ O1g,
    const __bf16* __restrict__ O2g,
    const int* __restrict__ rp_all,
    const int2* __restrict__ e1, const int2* __restrict__ e2,
    const float* __restrict__ b2, const float* __restrict__ b4,
    const float* __restrict__ Wl, const float* __restrict__ bl,
    float* __restrict__ out) {
  __shared__ float Wls[80 * NC];      // 12.8 KB
  __shared__ float cat[4][80];
  int t = threadIdx.x;
  for (int i = 0; i < 4; i++) {
    int idx = i * 256 + t;
    if (idx < 800) ((float4*)Wls)[idx] = ((const float4*)Wl)[idx];
  }
  __syncthreads();
  int wid = t >> 6, lane = t & 63;
  int d = blockIdx.x * 4 + wid;       // grid.x = 12500 exactly
  float o1 = 0.f, o2 = 0.f;
  if (lane < NC) {
    int beg = rp_all[d], end = rp_all[d + 1];
    int j = beg;
    for (; j + 1 < end; j += 2) {
      int2 ea = e1[j], eb = e1[j + 1];
      o1 = fmaf(__int_as_float(ea.y), (float)O1g[(size_t)ea.x * NC + lane], o1);
      o1 = fmaf(__int_as_float(eb.y), (float)O1g[(size_t)eb.x * NC + lane], o1);
    }
    if (j < end) o1 = fmaf(__int_as_float(e1[j].y), (float)O1g[(size_t)e1[j].x * NC + lane], o1);
    beg = rp_all[PADN + d]; end = rp_all[PADN + d + 1];
    j = beg;
    for (; j + 1 < end; j += 2) {
      int2 ea = e2[j], eb = e2[j + 1];
      o2 = fmaf(__int_as_float(ea.y), (float)O2g[(size_t)ea.x * NC + lane], o2);
      o2 = fmaf(__int_as_float(eb.y), (float)O2g[(size_t)eb.x * NC + lane], o2);
    }
    if (j < end) o2 = fmaf(__int_as_float(e2[j].y), (float)O2g[(size_t)e2[j].x * NC + lane], o2);
    o1 += b2[lane];
    o2 += b4[lane];
    cat[wid][lane] = o1;
    cat[wid][NC + lane] = o2;
  }
  __syncthreads();
  float g = 0.f;
  if (lane < NC) {
    for (int k = 0; k < 2 * NC; k++)
      g = fmaf(cat[wid][k], Wls[k * NC + lane], g);
    g = 1.f / (1.f + __expf(-(g + bl[lane])));
  }
  float val = (lane < NC) ? (g * o1 + (1.f - g) * o2) : -INFINITY;
  float m = val;
#pragma unroll
  for (int off = 32; off > 0; off >>= 1) m = fmaxf(m, __shfl_xor(m, off));
  float ex = (lane < NC) ? __expf(val - m) : 0.f;
  float s = ex;
#pragma unroll
  for (int off = 32; off > 0; off >>= 1) s += __shfl_xor(s, off);
  if (lane < NC) out[(size_t)d * NC + lane] = val - m - __logf(s);
}

// ---------------- host ----------------
extern "C" void kernel_launch(void* const* d_in, const int* in_sizes, int n_in,
                              void* d_out, int out_size, void* d_ws, size_t ws_size,
                              hipStream_t stream) {
  const float* x   = (const float*)d_in[0];
  const int*   ei1 = (const int*)d_in[1];
  const float* ev1 = (const float*)d_in[2];
  const int*   ei2 = (const int*)d_in[3];
  const float* ev2 = (const float*)d_in[4];
  const float* W1  = (const float*)d_in[5];
  const float* b1  = (const float*)d_in[6];
  const float* W2  = (const float*)d_in[7];
  const float* b2  = (const float*)d_in[8];
  const float* W3  = (const float*)d_in[9];
  const float* b3  = (const float*)d_in[10];
  const float* W4  = (const float*)d_in[11];
  const float* b4  = (const float*)d_in[12];
  const float* Wl  = (const float*)d_in[13];
  const float* bl  = (const float*)d_in[14];
  float* out = (float*)d_out;
  char* ws = (char*)d_ws;

  int*    deg  = (int*)(ws + O_DEG);
  int*    cur1 = (int*)(ws + O_CUR);
  int*    cur2 = (int*)(ws + O_CUR + PADN * 4);
  int*    part = (int*)(ws + O_PART);
  int*    rp   = (int*)(ws + O_RP);
  int2*   e1   = (int2*)(ws + O_E1);
  int2*   e2   = (int2*)(ws + O_E2);
  __bf16* Wbt  = (__bf16*)(ws + O_WBT);
  __bf16* XWb  = (__bf16*)(ws + O_XW);
  __bf16* h1   = (__bf16*)(ws + O_H1);
  __bf16* h2   = (__bf16*)(ws + O_H2);
  __bf16* O1   = (__bf16*)(ws + O_O1);
  __bf16* O2   = (__bf16*)(ws + O_O2);

  const int* src1 = ei1;
  const int* dst1 = ei1 + NE;
  const int* src2 = ei2;
  const int* dst2 = ei2 + NE;

  hipMemsetAsync(ws + O_DEG, 0, (size_t)4 * PADN * 4, stream);

  dim3 bs(256);
  k_degree<<<dim3((NE + 255) / 256), bs, 0, stream>>>(dst1, dst2, deg);
  k_chunk_sum<<<dim3(2 * NCHUNK), bs, 0, stream>>>(deg, part);
  k_scan_part<<<dim3(1), dim3(512), 0, stream>>>(part);
  k_chunk_scan<<<dim3(2 * NCHUNK), bs, 0, stream>>>(deg, part, rp);
  k_scatter<<<dim3((NE + 255) / 256), bs, 0, stream>>>(src1, dst1, ev1, rp, cur1, e1);
  k_scatter<<<dim3((NE + 255) / 256), bs, 0, stream>>>(src2, dst2, ev2, rp + PADN, cur2, e2);

  k_wcvt<<<dim3(512), bs, 0, stream>>>(W1, W3, Wbt);
  k_gemm1<<<dim3(MPAD / 128), dim3(512), 0, stream>>>(x, Wbt, XWb);
  k_spmm_h<<<dim3(NN / 4, 2), bs, 0, stream>>>(XWb, rp, e1, e2, b1, b3, h1, h2);
  k_gemm2<<<dim3((NN + G2R - 1) / G2R, 2), bs, 0, stream>>>(h1, h2, W2, W4, O1, O2);
  k_out<<<dim3(NN / 4), bs, 0, stream>>>(O1, O2, rp, e1, e2, b2, b4, Wl, bl, out);
}

// Round 6
// 546.701 us; speedup vs baseline: 1.4285x; 1.1036x over previous
//
#include <hip/hip_runtime.h>
#include <math.h>

#define NN 50000
#define NE 800000
#define NF 512
#define NH 128
#define NC 40
#define NCHUNK 196              // ceil(50000/256)
#define PADN (NCHUNK*256)       // 50176
#define MPAD 50048              // 391*128

typedef __bf16 bf16x8 __attribute__((ext_vector_type(8)));
typedef __bf16 bf16x2 __attribute__((ext_vector_type(2)));
typedef float f32x4 __attribute__((ext_vector_type(4)));

// ---------------- workspace layout (bytes) ----------------
#define O_DEG   0                     // 2*PADN ints (deg1|deg2)
#define O_CUR   401408                // 2*PADN ints (cur1|cur2)
#define O_PART  802816                // 392 ints (+pad)
#define O_RP    806912                // 2*PADN ints (rp_all, stride PADN)
#define O_E1    1208320               // NE int2 (src, val-bits)
#define O_E2    7608320               // NE int2
#define O_WBT   14008320              // 256*512 bf16
#define O_XW    14270464              // MPAD*256 bf16
#define O_H1    39895040              // MPAD*128 bf16
#define O_H2    52707328              // MPAD*128 bf16
#define O_O1    65519616              // MPAD*40 bf16
#define O_O2    69523456              // MPAD*40 bf16  (end 73527296)

// ---------------- CSC build ----------------
__global__ __launch_bounds__(256) void k_degree(const int* __restrict__ dst1,
                                                const int* __restrict__ dst2,
                                                int* __restrict__ deg) {
  int e = blockIdx.x * 256 + threadIdx.x;
  if (e < NE) {
    atomicAdd(&deg[dst1[e]], 1);
    atomicAdd(&deg[PADN + dst2[e]], 1);
  }
}

__global__ __launch_bounds__(256) void k_chunk_sum(const int* __restrict__ deg,
                                                   int* __restrict__ part) {
  __shared__ int sm[256];
  sm[threadIdx.x] = deg[blockIdx.x * 256 + threadIdx.x];
  __syncthreads();
  for (int off = 128; off > 0; off >>= 1) {
    if (threadIdx.x < off) sm[threadIdx.x] += sm[threadIdx.x + off];
    __syncthreads();
  }
  if (threadIdx.x == 0) part[blockIdx.x] = sm[0];
}

__global__ __launch_bounds__(512) void k_scan_part(int* __restrict__ part) {
  __shared__ int s[512];
  int t = threadIdx.x;
  int seg = t >> 8, i = t & 255;
  int active = (i < NCHUNK);
  int v = active ? part[seg * NCHUNK + i] : 0;
  s[t] = v;
  __syncthreads();
  for (int off = 1; off < 256; off <<= 1) {
    int u = (i >= off) ? s[seg * 256 + i - off] : 0;
    __syncthreads();
    s[t] += u;
    __syncthreads();
  }
  if (active) part[seg * NCHUNK + i] = s[t] - v;  // exclusive
}

__global__ __launch_bounds__(256) void k_chunk_scan(const int* __restrict__ deg,
                                                    const int* __restrict__ part,
                                                    int* __restrict__ rp_all) {
  __shared__ int s[256];
  int b = blockIdx.x;                 // 0..391
  int t = threadIdx.x;
  int v = deg[b * 256 + t];
  s[t] = v;
  __syncthreads();
  for (int off = 1; off < 256; off <<= 1) {
    int u = (t >= off) ? s[t - off] : 0;
    __syncthreads();
    s[t] += u;
    __syncthreads();
  }
  int seg = (b >= NCHUNK) ? 1 : 0;
  int lb = b - seg * NCHUNK;
  int lidx = lb * 256 + t;
  int excl = part[b] + s[t] - v;
  if (lidx <= NN) rp_all[seg * PADN + lidx] = excl;
}

// merged: both towers in one launch (blockIdx.y = tower), halves exposed latency
__global__ __launch_bounds__(256) void k_scatter2(const int* __restrict__ src1,
                                                  const int* __restrict__ dst1,
                                                  const float* __restrict__ val1,
                                                  const int* __restrict__ src2,
                                                  const int* __restrict__ dst2,
                                                  const float* __restrict__ val2,
                                                  const int* __restrict__ rp_all,
                                                  int* __restrict__ cur_all,
                                                  int2* __restrict__ e1,
                                                  int2* __restrict__ e2) {
  int tower = blockIdx.y;
  const int* src = tower ? src2 : src1;
  const int* dst = tower ? dst2 : dst1;
  const float* val = tower ? val2 : val1;
  const int* rp = rp_all + tower * PADN;
  int* cur = cur_all + tower * PADN;
  int2* ep = tower ? e2 : e1;
  int e = blockIdx.x * 256 + threadIdx.x;
  if (e < NE) {
    int d = dst[e];
    int p = atomicAdd(&cur[d], 1);
    ep[rp[d] + p] = make_int2(src[e], __float_as_int(val[e]));
  }
}

// ---------------- W -> bf16 transposed [256 n][512 k] ----------------
__global__ __launch_bounds__(256) void k_wcvt(const float* __restrict__ W1,
                                              const float* __restrict__ W3,
                                              __bf16* __restrict__ Wbt) {
  int k = blockIdx.x;                 // 0..511
  int t = threadIdx.x;                // 0..255 = output col
  float v = (t < 128) ? W1[k * 128 + t] : W3[k * 128 + (t - 128)];
  Wbt[(size_t)t * 512 + k] = (__bf16)v;
}

// ---------------- GEMM1 (MFMA): XW[MPAD,256]bf16 = x[N,512] @ [W1|W3] ----------------
__global__ __launch_bounds__(512) void k_gemm1(const float* __restrict__ x,
                                               const __bf16* __restrict__ Wbt,
                                               __bf16* __restrict__ XWb) {
  __shared__ __align__(16) char smem[49152];
  const int t = threadIdx.x;
  const int m0 = blockIdx.x * 128;
  const int lane = t & 63, wid = t >> 6;
  const int wm = wid >> 2, wn = wid & 3;
  const int lr = lane & 15, lk = lane >> 4;
  const int sw = (lr & 7) << 4;

  int arow[4], brow[4];
#pragma unroll
  for (int mi = 0; mi < 4; mi++) arow[mi] = (wm * 64 + mi * 16 + lr) * 128;
#pragma unroll
  for (int ni = 0; ni < 4; ni++) brow[ni] = 16384 + (wn * 64 + ni * 16 + lr) * 128;

  f32x4 acc[4][4];
#pragma unroll
  for (int mi = 0; mi < 4; mi++)
#pragma unroll
    for (int ni = 0; ni < 4; ni++) acc[mi][ni] = (f32x4){0.f, 0.f, 0.f, 0.f};

  for (int kt = 0; kt < 8; ++kt) {
    int k0 = kt * 64;
#pragma unroll
    for (int i = 0; i < 2; ++i) {
      int c = t + i * 512;
      int r = c >> 3, kq = c & 7;
      int grow = m0 + r;
      float4 f0, f1;
      if (grow < NN) {
        const float* p = x + (size_t)grow * NF + k0 + kq * 8;
        f0 = *(const float4*)p;
        f1 = *(const float4*)(p + 4);
      } else {
        f0 = make_float4(0.f, 0.f, 0.f, 0.f);
        f1 = f0;
      }
      bf16x8 ch;
      ch[0] = (__bf16)f0.x; ch[1] = (__bf16)f0.y; ch[2] = (__bf16)f0.z; ch[3] = (__bf16)f0.w;
      ch[4] = (__bf16)f1.x; ch[5] = (__bf16)f1.y; ch[6] = (__bf16)f1.z; ch[7] = (__bf16)f1.w;
      int addr = (r * 128 + kq * 16) ^ ((r & 7) << 4);
      *(bf16x8*)(smem + addr) = ch;
    }
#pragma unroll
    for (int i = 0; i < 4; ++i) {
      int c = t + i * 512;
      int n = c >> 3, kq = c & 7;
      bf16x8 ch = *(const bf16x8*)(Wbt + (size_t)n * 512 + k0 + kq * 8);
      int addr = 16384 + ((n * 128 + kq * 16) ^ ((n & 7) << 4));
      *(bf16x8*)(smem + addr) = ch;
    }
    __syncthreads();

#pragma unroll
    for (int kb = 0; kb < 2; ++kb) {
      int kbyte = (kb * 64 + lk * 16) ^ sw;
      bf16x8 af[4], bfr[4];
#pragma unroll
      for (int mi = 0; mi < 4; mi++) af[mi] = *(const bf16x8*)(smem + arow[mi] + kbyte);
#pragma unroll
      for (int ni = 0; ni < 4; ni++) bfr[ni] = *(const bf16x8*)(smem + brow[ni] + kbyte);
#pragma unroll
      for (int mi = 0; mi < 4; mi++)
#pragma unroll
        for (int ni = 0; ni < 4; ni++)
          acc[mi][ni] = __builtin_amdgcn_mfma_f32_16x16x32_bf16(af[mi], bfr[ni], acc[mi][ni], 0, 0, 0);
    }
    __syncthreads();
  }

#pragma unroll
  for (int mi = 0; mi < 4; mi++) {
#pragma unroll
    for (int ni = 0; ni < 4; ni++) {
#pragma unroll
      for (int reg = 0; reg < 4; reg++) {
        int row = m0 + wm * 64 + mi * 16 + lk * 4 + reg;
        int col = wn * 64 + ni * 16 + lr;
        XWb[(size_t)row * 256 + col] = (__bf16)acc[mi][ni][reg];
      }
    }
  }
}

// ---------------- SpMM layer1 (F=128 bf16) + bias + relu -> h bf16 ----------------
// unroll-4 batched edge loads: 4 record loads in flight, then 4 row-gathers in flight.
__global__ __launch_bounds__(256) void k_spmm_h(const __bf16* __restrict__ XWb,
    const int* __restrict__ rp_all,
    const int2* __restrict__ e1, const int2* __restrict__ e2,
    const float* __restrict__ b1, const float* __restrict__ b3,
    __bf16* __restrict__ h1, __bf16* __restrict__ h2) {
  int tower = blockIdx.y;
  const int* rp = rp_all + tower * PADN;
  const int2* ed = tower ? e2 : e1;
  const float* bias = tower ? b3 : b1;
  __bf16* hout = tower ? h2 : h1;
  int wid = threadIdx.x >> 6, lane = threadIdx.x & 63;
  int d = blockIdx.x * 4 + wid;       // grid.x = 12500 exactly
  int beg = rp[d], end = rp[d + 1];
  float a0 = 0.f, a1 = 0.f;
  const __bf16* base = XWb + tower * 128 + 2 * lane;
  int j = beg;
  for (; j + 3 < end; j += 4) {
    int2 r0 = ed[j], r1 = ed[j + 1], r2 = ed[j + 2], r3 = ed[j + 3];
    bf16x2 x0 = *(const bf16x2*)(base + (size_t)r0.x * 256);
    bf16x2 x1 = *(const bf16x2*)(base + (size_t)r1.x * 256);
    bf16x2 x2 = *(const bf16x2*)(base + (size_t)r2.x * 256);
    bf16x2 x3 = *(const bf16x2*)(base + (size_t)r3.x * 256);
    float v0 = __int_as_float(r0.y), v1 = __int_as_float(r1.y);
    float v2 = __int_as_float(r2.y), v3 = __int_as_float(r3.y);
    a0 = fmaf(v0, (float)x0[0], a0); a1 = fmaf(v0, (float)x0[1], a1);
    a0 = fmaf(v1, (float)x1[0], a0); a1 = fmaf(v1, (float)x1[1], a1);
    a0 = fmaf(v2, (float)x2[0], a0); a1 = fmaf(v2, (float)x2[1], a1);
    a0 = fmaf(v3, (float)x3[0], a0); a1 = fmaf(v3, (float)x3[1], a1);
  }
  for (; j < end; ++j) {
    int2 r0 = ed[j];
    float v0 = __int_as_float(r0.y);
    bf16x2 x0 = *(const bf16x2*)(base + (size_t)r0.x * 256);
    a0 = fmaf(v0, (float)x0[0], a0); a1 = fmaf(v0, (float)x0[1], a1);
  }
  float o0 = fmaxf(a0 + bias[2 * lane], 0.f);
  float o1 = fmaxf(a1 + bias[2 * lane + 1], 0.f);
  bf16x2 hv; hv[0] = (__bf16)o0; hv[1] = (__bf16)o1;
  *(bf16x2*)(hout + (size_t)d * NH + 2 * lane) = hv;
}

// ---------------- GEMM2: O[N,40]bf16 = h[N,128]bf16 @ W (fp32 compute) ----------------
#define G2R 32
__global__ __launch_bounds__(256) void k_gemm2(const __bf16* __restrict__ h1,
                                               const __bf16* __restrict__ h2,
                                               const float* __restrict__ W2,
                                               const float* __restrict__ W4,
                                               __bf16* __restrict__ O1,
                                               __bf16* __restrict__ O2) {
  int tower = blockIdx.y;
  const __bf16* h = tower ? h2 : h1;
  const float* W = tower ? W4 : W2;
  __bf16* O = tower ? O2 : O1;
  __shared__ float hs[G2R * 132];     // padded stride 132
  __shared__ float Ws[NH * NC];       // 20 KB
  int t = threadIdx.x;
  int r0 = blockIdx.x * G2R;
  for (int i = 0; i < 5; i++)
    ((float4*)Ws)[i * 256 + t] = ((const float4*)W)[i * 256 + t];
#pragma unroll
  for (int i = 0; i < 2; i++) {
    int c = i * 256 + t;
    int row = c >> 4, c8 = c & 15;
    bf16x8 raw;
    if (r0 + row < NN) raw = *(const bf16x8*)(h + (size_t)(r0 + row) * NH + c8 * 8);
    else { bf16x8 z = {}; raw = z; }
    float4 lo = make_float4((float)raw[0], (float)raw[1], (float)raw[2], (float)raw[3]);
    float4 hi = make_float4((float)raw[4], (float)raw[5], (float)raw[6], (float)raw[7]);
    *(float4*)(hs + row * 132 + c8 * 8) = lo;
    *(float4*)(hs + row * 132 + c8 * 8 + 4) = hi;
  }
  __syncthreads();
  int r = t >> 3, cj = t & 7;
  float acc[5] = {0.f, 0.f, 0.f, 0.f, 0.f};
  for (int k4 = 0; k4 < NH / 4; k4++) {
    float4 hv = ((const float4*)(hs + r * 132))[k4];
    int k = k4 * 4;
#pragma unroll
    for (int j = 0; j < 5; j++) acc[j] = fmaf(hv.x, Ws[(k + 0) * NC + cj * 5 + j], acc[j]);
#pragma unroll
    for (int j = 0; j < 5; j++) acc[j] = fmaf(hv.y, Ws[(k + 1) * NC + cj * 5 + j], acc[j]);
#pragma unroll
    for (int j = 0; j < 5; j++) acc[j] = fmaf(hv.z, Ws[(k + 2) * NC + cj * 5 + j], acc[j]);
#pragma unroll
    for (int j = 0; j < 5; j++) acc[j] = fmaf(hv.w, Ws[(k + 3) * NC + cj * 5 + j], acc[j]);
  }
  if (r0 + r < NN) {
#pragma unroll
    for (int j = 0; j < 5; j++)
      O[(size_t)(r0 + r) * NC + cj * 5 + j] = (__bf16)acc[j];
  }
}

// ------- fused: spmm2 (both towers, bf16 gather, unroll-4) + bias + gate + log_softmax -------
__global__ __launch_bounds__(256) void k_out(const __bf16* __restrict__ O1g,
    const __bf16* __restrict__ O2g,
    const int* __restrict__ rp_all,
    const int2* __restrict__ e1, const int2* __restrict__ e2,
    const float* __restrict__ b2, const float* __restrict__ b4,
    const float* __restrict__ Wl, const float* __restrict__ bl,
    float* __restrict__ out) {
  __shared__ float Wls[80 * NC];      // 12.8 KB
  __shared__ float cat[4][80];
  int t = threadIdx.x;
  for (int i = 0; i < 4; i++) {
    int idx = i * 256 + t;
    if (idx < 800) ((float4*)Wls)[idx] = ((const float4*)Wl)[idx];
  }
  __syncthreads();
  int wid = t >> 6, lane = t & 63;
  int d = blockIdx.x * 4 + wid;       // grid.x = 12500 exactly
  float o1 = 0.f, o2 = 0.f;
  if (lane < NC) {
    int beg = rp_all[d], end = rp_all[d + 1];
    int j = beg;
    for (; j + 3 < end; j += 4) {
      int2 r0 = e1[j], r1 = e1[j + 1], r2 = e1[j + 2], r3 = e1[j + 3];
      float g0 = (float)O1g[(size_t)r0.x * NC + lane];
      float g1 = (float)O1g[(size_t)r1.x * NC + lane];
      float g2 = (float)O1g[(size_t)r2.x * NC + lane];
      float g3 = (float)O1g[(size_t)r3.x * NC + lane];
      o1 = fmaf(__int_as_float(r0.y), g0, o1);
      o1 = fmaf(__int_as_float(r1.y), g1, o1);
      o1 = fmaf(__int_as_float(r2.y), g2, o1);
      o1 = fmaf(__int_as_float(r3.y), g3, o1);
    }
    for (; j < end; ++j)
      o1 = fmaf(__int_as_float(e1[j].y), (float)O1g[(size_t)e1[j].x * NC + lane], o1);
    beg = rp_all[PADN + d]; end = rp_all[PADN + d + 1];
    j = beg;
    for (; j + 3 < end; j += 4) {
      int2 r0 = e2[j], r1 = e2[j + 1], r2 = e2[j + 2], r3 = e2[j + 3];
      float g0 = (float)O2g[(size_t)r0.x * NC + lane];
      float g1 = (float)O2g[(size_t)r1.x * NC + lane];
      float g2 = (float)O2g[(size_t)r2.x * NC + lane];
      float g3 = (float)O2g[(size_t)r3.x * NC + lane];
      o2 = fmaf(__int_as_float(r0.y), g0, o2);
      o2 = fmaf(__int_as_float(r1.y), g1, o2);
      o2 = fmaf(__int_as_float(r2.y), g2, o2);
      o2 = fmaf(__int_as_float(r3.y), g3, o2);
    }
    for (; j < end; ++j)
      o2 = fmaf(__int_as_float(e2[j].y), (float)O2g[(size_t)e2[j].x * NC + lane], o2);
    o1 += b2[lane];
    o2 += b4[lane];
    cat[wid][lane] = o1;
    cat[wid][NC + lane] = o2;
  }
  __syncthreads();
  float g = 0.f;
  if (lane < NC) {
    for (int k = 0; k < 2 * NC; k++)
      g = fmaf(cat[wid][k], Wls[k * NC + lane], g);
    g = 1.f / (1.f + __expf(-(g + bl[lane])));
  }
  float val = (lane < NC) ? (g * o1 + (1.f - g) * o2) : -INFINITY;
  float m = val;
#pragma unroll
  for (int off = 32; off > 0; off >>= 1) m = fmaxf(m, __shfl_xor(m, off));
  float ex = (lane < NC) ? __expf(val - m) : 0.f;
  float s = ex;
#pragma unroll
  for (int off = 32; off > 0; off >>= 1) s += __shfl_xor(s, off);
  if (lane < NC) out[(size_t)d * NC + lane] = val - m - __logf(s);
}

// ---------------- host ----------------
extern "C" void kernel_launch(void* const* d_in, const int* in_sizes, int n_in,
                              void* d_out, int out_size, void* d_ws, size_t ws_size,
                              hipStream_t stream) {
  const float* x   = (const float*)d_in[0];
  const int*   ei1 = (const int*)d_in[1];
  const float* ev1 = (const float*)d_in[2];
  const int*   ei2 = (const int*)d_in[3];
  const float* ev2 = (const float*)d_in[4];
  const float* W1  = (const float*)d_in[5];
  const float* b1  = (const float*)d_in[6];
  const float* W2  = (const float*)d_in[7];
  const float* b2  = (const float*)d_in[8];
  const float* W3  = (const float*)d_in[9];
  const float* b3  = (const float*)d_in[10];
  const float* W4  = (const float*)d_in[11];
  const float* b4  = (const float*)d_in[12];
  const float* Wl  = (const float*)d_in[13];
  const float* bl  = (const float*)d_in[14];
  float* out = (float*)d_out;
  char* ws = (char*)d_ws;

  int*    deg  = (int*)(ws + O_DEG);
  int*    cur  = (int*)(ws + O_CUR);       // cur_all, stride PADN
  int*    part = (int*)(ws + O_PART);
  int*    rp   = (int*)(ws + O_RP);        // rp_all, stride PADN
  int2*   e1   = (int2*)(ws + O_E1);
  int2*   e2   = (int2*)(ws + O_E2);
  __bf16* Wbt  = (__bf16*)(ws + O_WBT);
  __bf16* XWb  = (__bf16*)(ws + O_XW);
  __bf16* h1   = (__bf16*)(ws + O_H1);
  __bf16* h2   = (__bf16*)(ws + O_H2);
  __bf16* O1   = (__bf16*)(ws + O_O1);
  __bf16* O2   = (__bf16*)(ws + O_O2);

  const int* src1 = ei1;
  const int* dst1 = ei1 + NE;
  const int* src2 = ei2;
  const int* dst2 = ei2 + NE;

  hipMemsetAsync(ws + O_DEG, 0, (size_t)4 * PADN * 4, stream);

  dim3 bs(256);
  k_degree<<<dim3((NE + 255) / 256), bs, 0, stream>>>(dst1, dst2, deg);
  k_chunk_sum<<<dim3(2 * NCHUNK), bs, 0, stream>>>(deg, part);
  k_scan_part<<<dim3(1), dim3(512), 0, stream>>>(part);
  k_chunk_scan<<<dim3(2 * NCHUNK), bs, 0, stream>>>(deg, part, rp);
  k_scatter2<<<dim3((NE + 255) / 256, 2), bs, 0, stream>>>(src1, dst1, ev1,
                                                           src2, dst2, ev2,
                                                           rp, cur, e1, e2);

  k_wcvt<<<dim3(512), bs, 0, stream>>>(W1, W3, Wbt);
  k_gemm1<<<dim3(MPAD / 128), dim3(512), 0, stream>>>(x, Wbt, XWb);
  k_spmm_h<<<dim3(NN / 4, 2), bs, 0, stream>>>(XWb, rp, e1, e2, b1, b3, h1, h2);
  k_gemm2<<<dim3((NN + G2R - 1) / G2R, 2), bs, 0, stream>>>(h1, h2, W2, W4, O1, O2);
  k_out<<<dim3(NN / 4), bs, 0, stream>>>(O1, O2, rp, e1, e2, b2, b4, Wl, bl, out);
}

// Round 8
// 528.589 us; speedup vs baseline: 1.4774x; 1.0343x over previous
//
#include <hip/hip_runtime.h>
#include <math.h>

#define NN 50000
#define NE 800000
#define NF 512
#define NH 128
#define NC 40
#define NCHUNK 196              // ceil(50000/256)
#define PADN (NCHUNK*256)       // 50176
#define MPAD 50048              // 391*128

typedef __bf16 bf16x8 __attribute__((ext_vector_type(8)));
typedef __bf16 bf16x2 __attribute__((ext_vector_type(2)));
typedef float f32x4 __attribute__((ext_vector_type(4)));

// ---------------- workspace layout (bytes) ----------------
#define O_DEG   0                     // 2*PADN ints (deg1|deg2)
#define O_CUR   401408                // 2*PADN ints (cur1|cur2)
#define O_PART  802816                // 392 ints (+pad)
#define O_RP    806912                // 2*PADN ints (rp_all, stride PADN)
#define O_E1    1208320               // NE int2 (src, val-bits)
#define O_E2    7608320               // NE int2
#define O_WBT   14008320              // 256*512 bf16
#define O_XW    14270464              // MPAD*256 bf16
#define O_H1    39895040              // MPAD*128 bf16
#define O_H2    52707328              // MPAD*128 bf16
#define O_O1    65519616              // MPAD*40 bf16
#define O_O2    69523456              // MPAD*40 bf16  (end 73527296)

// ---------------- CSC build ----------------
__global__ __launch_bounds__(256) void k_degree(const int* __restrict__ dst1,
                                                const int* __restrict__ dst2,
                                                int* __restrict__ deg) {
  int e = blockIdx.x * 256 + threadIdx.x;
  if (e < NE) {
    atomicAdd(&deg[dst1[e]], 1);
    atomicAdd(&deg[PADN + dst2[e]], 1);
  }
}

__global__ __launch_bounds__(256) void k_chunk_sum(const int* __restrict__ deg,
                                                   int* __restrict__ part) {
  __shared__ int sm[256];
  sm[threadIdx.x] = deg[blockIdx.x * 256 + threadIdx.x];
  __syncthreads();
  for (int off = 128; off > 0; off >>= 1) {
    if (threadIdx.x < off) sm[threadIdx.x] += sm[threadIdx.x + off];
    __syncthreads();
  }
  if (threadIdx.x == 0) part[blockIdx.x] = sm[0];
}

__global__ __launch_bounds__(512) void k_scan_part(int* __restrict__ part) {
  __shared__ int s[512];
  int t = threadIdx.x;
  int seg = t >> 8, i = t & 255;
  int active = (i < NCHUNK);
  int v = active ? part[seg * NCHUNK + i] : 0;
  s[t] = v;
  __syncthreads();
  for (int off = 1; off < 256; off <<= 1) {
    int u = (i >= off) ? s[seg * 256 + i - off] : 0;
    __syncthreads();
    s[t] += u;
    __syncthreads();
  }
  if (active) part[seg * NCHUNK + i] = s[t] - v;  // exclusive
}

__global__ __launch_bounds__(256) void k_chunk_scan(const int* __restrict__ deg,
                                                    const int* __restrict__ part,
                                                    int* __restrict__ rp_all) {
  __shared__ int s[256];
  int b = blockIdx.x;                 // 0..391
  int t = threadIdx.x;
  int v = deg[b * 256 + t];
  s[t] = v;
  __syncthreads();
  for (int off = 1; off < 256; off <<= 1) {
    int u = (t >= off) ? s[t - off] : 0;
    __syncthreads();
    s[t] += u;
    __syncthreads();
  }
  int seg = (b >= NCHUNK) ? 1 : 0;
  int lb = b - seg * NCHUNK;
  int lidx = lb * 256 + t;
  int excl = part[b] + s[t] - v;
  if (lidx <= NN) rp_all[seg * PADN + lidx] = excl;
}

// merged: both towers in one launch (blockIdx.y = tower)
__global__ __launch_bounds__(256) void k_scatter2(const int* __restrict__ src1,
                                                  const int* __restrict__ dst1,
                                                  const float* __restrict__ val1,
                                                  const int* __restrict__ src2,
                                                  const int* __restrict__ dst2,
                                                  const float* __restrict__ val2,
                                                  const int* __restrict__ rp_all,
                                                  int* __restrict__ cur_all,
                                                  int2* __restrict__ e1,
                                                  int2* __restrict__ e2) {
  int tower = blockIdx.y;
  const int* src = tower ? src2 : src1;
  const int* dst = tower ? dst2 : dst1;
  const float* val = tower ? val2 : val1;
  const int* rp = rp_all + tower * PADN;
  int* cur = cur_all + tower * PADN;
  int2* ep = tower ? e2 : e1;
  int e = blockIdx.x * 256 + threadIdx.x;
  if (e < NE) {
    int d = dst[e];
    int p = atomicAdd(&cur[d], 1);
    ep[rp[d] + p] = make_int2(src[e], __float_as_int(val[e]));
  }
}

// ---------------- W -> bf16 transposed [256 n][512 k] ----------------
__global__ __launch_bounds__(256) void k_wcvt(const float* __restrict__ W1,
                                              const float* __restrict__ W3,
                                              __bf16* __restrict__ Wbt) {
  int k = blockIdx.x;                 // 0..511
  int t = threadIdx.x;                // 0..255 = output col
  float v = (t < 128) ? W1[k * 128 + t] : W3[k * 128 + (t - 128)];
  Wbt[(size_t)t * 512 + k] = (__bf16)v;
}

// ---------------- GEMM1 (MFMA): XW[MPAD,256]bf16 = x[N,512] @ [W1|W3] ----------------
__global__ __launch_bounds__(512) void k_gemm1(const float* __restrict__ x,
                                               const __bf16* __restrict__ Wbt,
                                               __bf16* __restrict__ XWb) {
  __shared__ __align__(16) char smem[49152];
  const int t = threadIdx.x;
  const int m0 = blockIdx.x * 128;
  const int lane = t & 63, wid = t >> 6;
  const int wm = wid >> 2, wn = wid & 3;
  const int lr = lane & 15, lk = lane >> 4;
  const int sw = (lr & 7) << 4;

  int arow[4], brow[4];
#pragma unroll
  for (int mi = 0; mi < 4; mi++) arow[mi] = (wm * 64 + mi * 16 + lr) * 128;
#pragma unroll
  for (int ni = 0; ni < 4; ni++) brow[ni] = 16384 + (wn * 64 + ni * 16 + lr) * 128;

  f32x4 acc[4][4];
#pragma unroll
  for (int mi = 0; mi < 4; mi++)
#pragma unroll
    for (int ni = 0; ni < 4; ni++) acc[mi][ni] = (f32x4){0.f, 0.f, 0.f, 0.f};

  for (int kt = 0; kt < 8; ++kt) {
    int k0 = kt * 64;
#pragma unroll
    for (int i = 0; i < 2; ++i) {
      int c = t + i * 512;
      int r = c >> 3, kq = c & 7;
      int grow = m0 + r;
      float4 f0, f1;
      if (grow < NN) {
        const float* p = x + (size_t)grow * NF + k0 + kq * 8;
        f0 = *(const float4*)p;
        f1 = *(const float4*)(p + 4);
      } else {
        f0 = make_float4(0.f, 0.f, 0.f, 0.f);
        f1 = f0;
      }
      bf16x8 ch;
      ch[0] = (__bf16)f0.x; ch[1] = (__bf16)f0.y; ch[2] = (__bf16)f0.z; ch[3] = (__bf16)f0.w;
      ch[4] = (__bf16)f1.x; ch[5] = (__bf16)f1.y; ch[6] = (__bf16)f1.z; ch[7] = (__bf16)f1.w;
      int addr = (r * 128 + kq * 16) ^ ((r & 7) << 4);
      *(bf16x8*)(smem + addr) = ch;
    }
#pragma unroll
    for (int i = 0; i < 4; ++i) {
      int c = t + i * 512;
      int n = c >> 3, kq = c & 7;
      bf16x8 ch = *(const bf16x8*)(Wbt + (size_t)n * 512 + k0 + kq * 8);
      int addr = 16384 + ((n * 128 + kq * 16) ^ ((n & 7) << 4));
      *(bf16x8*)(smem + addr) = ch;
    }
    __syncthreads();

#pragma unroll
    for (int kb = 0; kb < 2; ++kb) {
      int kbyte = (kb * 64 + lk * 16) ^ sw;
      bf16x8 af[4], bfr[4];
#pragma unroll
      for (int mi = 0; mi < 4; mi++) af[mi] = *(const bf16x8*)(smem + arow[mi] + kbyte);
#pragma unroll
      for (int ni = 0; ni < 4; ni++) bfr[ni] = *(const bf16x8*)(smem + brow[ni] + kbyte);
#pragma unroll
      for (int mi = 0; mi < 4; mi++)
#pragma unroll
        for (int ni = 0; ni < 4; ni++)
          acc[mi][ni] = __builtin_amdgcn_mfma_f32_16x16x32_bf16(af[mi], bfr[ni], acc[mi][ni], 0, 0, 0);
    }
    __syncthreads();
  }

#pragma unroll
  for (int mi = 0; mi < 4; mi++) {
#pragma unroll
    for (int ni = 0; ni < 4; ni++) {
#pragma unroll
      for (int reg = 0; reg < 4; reg++) {
        int row = m0 + wm * 64 + mi * 16 + lk * 4 + reg;
        int col = wn * 64 + ni * 16 + lr;
        XWb[(size_t)row * 256 + col] = (__bf16)acc[mi][ni][reg];
      }
    }
  }
}

// ---------------- SpMM layer1 (F=128 bf16) + bias + relu -> h bf16 ----------------
// One wave owns TWO dst nodes; their edge loops interleave 4+4 -> 8 gathers in flight.
__global__ __launch_bounds__(256) void k_spmm_h(const __bf16* __restrict__ XWb,
    const int* __restrict__ rp_all,
    const int2* __restrict__ e1, const int2* __restrict__ e2,
    const float* __restrict__ b1, const float* __restrict__ b3,
    __bf16* __restrict__ h1, __bf16* __restrict__ h2) {
  int tower = blockIdx.y;
  const int* rp = rp_all + tower * PADN;
  const int2* ed = tower ? e2 : e1;
  const float* bias = tower ? b3 : b1;
  __bf16* hout = tower ? h2 : h1;
  int wid = threadIdx.x >> 6, lane = threadIdx.x & 63;
  int dA = blockIdx.x * 8 + wid * 2;  // grid.x = 6250 exactly
  int dB = dA + 1;
  int jA = rp[dA], eA = rp[dA + 1];
  int jB = rp[dB], eB = rp[dB + 1];
  float a0 = 0.f, a1 = 0.f, c0 = 0.f, c1 = 0.f;
  const __bf16* base = XWb + tower * 128 + 2 * lane;

  // interleaved main loop: 8 record loads, then 8 row-gathers in flight
  while (jA + 3 < eA && jB + 3 < eB) {
    int2 rA0 = ed[jA], rA1 = ed[jA + 1], rA2 = ed[jA + 2], rA3 = ed[jA + 3];
    int2 rB0 = ed[jB], rB1 = ed[jB + 1], rB2 = ed[jB + 2], rB3 = ed[jB + 3];
    bf16x2 xA0 = *(const bf16x2*)(base + (size_t)rA0.x * 256);
    bf16x2 xA1 = *(const bf16x2*)(base + (size_t)rA1.x * 256);
    bf16x2 xA2 = *(const bf16x2*)(base + (size_t)rA2.x * 256);
    bf16x2 xA3 = *(const bf16x2*)(base + (size_t)rA3.x * 256);
    bf16x2 xB0 = *(const bf16x2*)(base + (size_t)rB0.x * 256);
    bf16x2 xB1 = *(const bf16x2*)(base + (size_t)rB1.x * 256);
    bf16x2 xB2 = *(const bf16x2*)(base + (size_t)rB2.x * 256);
    bf16x2 xB3 = *(const bf16x2*)(base + (size_t)rB3.x * 256);
    float vA0 = __int_as_float(rA0.y), vA1 = __int_as_float(rA1.y);
    float vA2 = __int_as_float(rA2.y), vA3 = __int_as_float(rA3.y);
    float vB0 = __int_as_float(rB0.y), vB1 = __int_as_float(rB1.y);
    float vB2 = __int_as_float(rB2.y), vB3 = __int_as_float(rB3.y);
    a0 = fmaf(vA0, (float)xA0[0], a0); a1 = fmaf(vA0, (float)xA0[1], a1);
    a0 = fmaf(vA1, (float)xA1[0], a0); a1 = fmaf(vA1, (float)xA1[1], a1);
    a0 = fmaf(vA2, (float)xA2[0], a0); a1 = fmaf(vA2, (float)xA2[1], a1);
    a0 = fmaf(vA3, (float)xA3[0], a0); a1 = fmaf(vA3, (float)xA3[1], a1);
    c0 = fmaf(vB0, (float)xB0[0], c0); c1 = fmaf(vB0, (float)xB0[1], c1);
    c0 = fmaf(vB1, (float)xB1[0], c0); c1 = fmaf(vB1, (float)xB1[1], c1);
    c0 = fmaf(vB2, (float)xB2[0], c0); c1 = fmaf(vB2, (float)xB2[1], c1);
    c0 = fmaf(vB3, (float)xB3[0], c0); c1 = fmaf(vB3, (float)xB3[1], c1);
    jA += 4; jB += 4;
  }
  // drain A
  for (; jA + 3 < eA; jA += 4) {
    int2 r0 = ed[jA], r1 = ed[jA + 1], r2 = ed[jA + 2], r3 = ed[jA + 3];
    bf16x2 x0 = *(const bf16x2*)(base + (size_t)r0.x * 256);
    bf16x2 x1 = *(const bf16x2*)(base + (size_t)r1.x * 256);
    bf16x2 x2 = *(const bf16x2*)(base + (size_t)r2.x * 256);
    bf16x2 x3 = *(const bf16x2*)(base + (size_t)r3.x * 256);
    float v0 = __int_as_float(r0.y), v1 = __int_as_float(r1.y);
    float v2 = __int_as_float(r2.y), v3 = __int_as_float(r3.y);
    a0 = fmaf(v0, (float)x0[0], a0); a1 = fmaf(v0, (float)x0[1], a1);
    a0 = fmaf(v1, (float)x1[0], a0); a1 = fmaf(v1, (float)x1[1], a1);
    a0 = fmaf(v2, (float)x2[0], a0); a1 = fmaf(v2, (float)x2[1], a1);
    a0 = fmaf(v3, (float)x3[0], a0); a1 = fmaf(v3, (float)x3[1], a1);
  }
  for (; jA < eA; ++jA) {
    int2 r0 = ed[jA];
    float v0 = __int_as_float(r0.y);
    bf16x2 x0 = *(const bf16x2*)(base + (size_t)r0.x * 256);
    a0 = fmaf(v0, (float)x0[0], a0); a1 = fmaf(v0, (float)x0[1], a1);
  }
  // drain B
  for (; jB + 3 < eB; jB += 4) {
    int2 r0 = ed[jB], r1 = ed[jB + 1], r2 = ed[jB + 2], r3 = ed[jB + 3];
    bf16x2 x0 = *(const bf16x2*)(base + (size_t)r0.x * 256);
    bf16x2 x1 = *(const bf16x2*)(base + (size_t)r1.x * 256);
    bf16x2 x2 = *(const bf16x2*)(base + (size_t)r2.x * 256);
    bf16x2 x3 = *(const bf16x2*)(base + (size_t)r3.x * 256);
    float v0 = __int_as_float(r0.y), v1 = __int_as_float(r1.y);
    float v2 = __int_as_float(r2.y), v3 = __int_as_float(r3.y);
    c0 = fmaf(v0, (float)x0[0], c0); c1 = fmaf(v0, (float)x0[1], c1);
    c0 = fmaf(v1, (float)x1[0], c0); c1 = fmaf(v1, (float)x1[1], c1);
    c0 = fmaf(v2, (float)x2[0], c0); c1 = fmaf(v2, (float)x2[1], c1);
    c0 = fmaf(v3, (float)x3[0], c0); c1 = fmaf(v3, (float)x3[1], c1);
  }
  for (; jB < eB; ++jB) {
    int2 r0 = ed[jB];
    float v0 = __int_as_float(r0.y);
    bf16x2 x0 = *(const bf16x2*)(base + (size_t)r0.x * 256);
    c0 = fmaf(v0, (float)x0[0], c0); c1 = fmaf(v0, (float)x0[1], c1);
  }

  float bl0 = bias[2 * lane], bl1 = bias[2 * lane + 1];
  bf16x2 hA; hA[0] = (__bf16)fmaxf(a0 + bl0, 0.f); hA[1] = (__bf16)fmaxf(a1 + bl1, 0.f);
  bf16x2 hB; hB[0] = (__bf16)fmaxf(c0 + bl0, 0.f); hB[1] = (__bf16)fmaxf(c1 + bl1, 0.f);
  *(bf16x2*)(hout + (size_t)dA * NH + 2 * lane) = hA;
  *(bf16x2*)(hout + (size_t)dB * NH + 2 * lane) = hB;
}

// ---------------- GEMM2: O[N,40]bf16 = h[N,128]bf16 @ W (fp32 compute) ----------------
#define G2R 32
__global__ __launch_bounds__(256) void k_gemm2(const __bf16* __restrict__ h1,
                                               const __bf16* __restrict__ h2,
                                               const float* __restrict__ W2,
                                               const float* __restrict__ W4,
                                               __bf16* __restrict__ O1,
                                               __bf16* __restrict__ O2) {
  int tower = blockIdx.y;
  const __bf16* h = tower ? h2 : h1;
  const float* W = tower ? W4 : W2;
  __bf16* O = tower ? O2 : O1;
  __shared__ float hs[G2R * 132];     // padded stride 132
  __shared__ float Ws[NH * NC];       // 20 KB
  int t = threadIdx.x;
  int r0 = blockIdx.x * G2R;
  for (int i = 0; i < 5; i++)
    ((float4*)Ws)[i * 256 + t] = ((const float4*)W)[i * 256 + t];
#pragma unroll
  for (int i = 0; i < 2; i++) {
    int c = i * 256 + t;
    int row = c >> 4, c8 = c & 15;
    bf16x8 raw;
    if (r0 + row < NN) raw = *(const bf16x8*)(h + (size_t)(r0 + row) * NH + c8 * 8);
    else { bf16x8 z = {}; raw = z; }
    float4 lo = make_float4((float)raw[0], (float)raw[1], (float)raw[2], (float)raw[3]);
    float4 hi = make_float4((float)raw[4], (float)raw[5], (float)raw[6], (float)raw[7]);
    *(float4*)(hs + row * 132 + c8 * 8) = lo;
    *(float4*)(hs + row * 132 + c8 * 8 + 4) = hi;
  }
  __syncthreads();
  int r = t >> 3, cj = t & 7;
  float acc[5] = {0.f, 0.f, 0.f, 0.f, 0.f};
  for (int k4 = 0; k4 < NH / 4; k4++) {
    float4 hv = ((const float4*)(hs + r * 132))[k4];
    int k = k4 * 4;
#pragma unroll
    for (int j = 0; j < 5; j++) acc[j] = fmaf(hv.x, Ws[(k + 0) * NC + cj * 5 + j], acc[j]);
#pragma unroll
    for (int j = 0; j < 5; j++) acc[j] = fmaf(hv.y, Ws[(k + 1) * NC + cj * 5 + j], acc[j]);
#pragma unroll
    for (int j = 0; j < 5; j++) acc[j] = fmaf(hv.z, Ws[(k + 2) * NC + cj * 5 + j], acc[j]);
#pragma unroll
    for (int j = 0; j < 5; j++) acc[j] = fmaf(hv.w, Ws[(k + 3) * NC + cj * 5 + j], acc[j]);
  }
  if (r0 + r < NN) {
#pragma unroll
    for (int j = 0; j < 5; j++)
      O[(size_t)(r0 + r) * NC + cj * 5 + j] = (__bf16)acc[j];
  }
}

// ------- fused: spmm2 (both towers INTERLEAVED -> 8 gathers in flight) + gate + log_softmax -------
__global__ __launch_bounds__(256) void k_out(const __bf16* __restrict__ O1g,
    const __bf16* __restrict__ O2g,
    const int* __restrict__ rp_all,
    const int2* __restrict__ e1, const int2* __restrict__ e2,
    const float* __restrict__ b2, const float* __restrict__ b4,
    const float* __restrict__ Wl, const float* __restrict__ bl,
    float* __restrict__ out) {
  __shared__ float Wls[80 * NC];      // 12.8 KB
  __shared__ float cat[4][80];
  int t = threadIdx.x;
  for (int i = 0; i < 4; i++) {
    int idx = i * 256 + t;
    if (idx < 800) ((float4*)Wls)[idx] = ((const float4*)Wl)[idx];
  }
  __syncthreads();
  int wid = t >> 6, lane = t & 63;
  int d = blockIdx.x * 4 + wid;       // grid.x = 12500 exactly
  float o1 = 0.f, o2 = 0.f;
  if (lane < NC) {
    int j1 = rp_all[d], E1 = rp_all[d + 1];
    int j2 = rp_all[PADN + d], E2 = rp_all[PADN + d + 1];
    // interleaved main loop: 8 record loads + 8 gathers in flight
    while (j1 + 3 < E1 && j2 + 3 < E2) {
      int2 rA0 = e1[j1], rA1 = e1[j1 + 1], rA2 = e1[j1 + 2], rA3 = e1[j1 + 3];
      int2 rB0 = e2[j2], rB1 = e2[j2 + 1], rB2 = e2[j2 + 2], rB3 = e2[j2 + 3];
      float gA0 = (float)O1g[(size_t)rA0.x * NC + lane];
      float gA1 = (float)O1g[(size_t)rA1.x * NC + lane];
      float gA2 = (float)O1g[(size_t)rA2.x * NC + lane];
      float gA3 = (float)O1g[(size_t)rA3.x * NC + lane];
      float gB0 = (float)O2g[(size_t)rB0.x * NC + lane];
      float gB1 = (float)O2g[(size_t)rB1.x * NC + lane];
      float gB2 = (float)O2g[(size_t)rB2.x * NC + lane];
      float gB3 = (float)O2g[(size_t)rB3.x * NC + lane];
      o1 = fmaf(__int_as_float(rA0.y), gA0, o1);
      o1 = fmaf(__int_as_float(rA1.y), gA1, o1);
      o1 = fmaf(__int_as_float(rA2.y), gA2, o1);
      o1 = fmaf(__int_as_float(rA3.y), gA3, o1);
      o2 = fmaf(__int_as_float(rB0.y), gB0, o2);
      o2 = fmaf(__int_as_float(rB1.y), gB1, o2);
      o2 = fmaf(__int_as_float(rB2.y), gB2, o2);
      o2 = fmaf(__int_as_float(rB3.y), gB3, o2);
      j1 += 4; j2 += 4;
    }
    for (; j1 + 3 < E1; j1 += 4) {
      int2 r0 = e1[j1], r1 = e1[j1 + 1], r2 = e1[j1 + 2], r3 = e1[j1 + 3];
      float g0 = (float)O1g[(size_t)r0.x * NC + lane];
      float g1 = (float)O1g[(size_t)r1.x * NC + lane];
      float g2 = (float)O1g[(size_t)r2.x * NC + lane];
      float g3 = (float)O1g[(size_t)r3.x * NC + lane];
      o1 = fmaf(__int_as_float(r0.y), g0, o1);
      o1 = fmaf(__int_as_float(r1.y), g1, o1);
      o1 = fmaf(__int_as_float(r2.y), g2, o1);
      o1 = fmaf(__int_as_float(r3.y), g3, o1);
    }
    for (; j1 < E1; ++j1)
      o1 = fmaf(__int_as_float(e1[j1].y), (float)O1g[(size_t)e1[j1].x * NC + lane], o1);
    for (; j2 + 3 < E2; j2 += 4) {
      int2 r0 = e2[j2], r1 = e2[j2 + 1], r2 = e2[j2 + 2], r3 = e2[j2 + 3];
      float g0 = (float)O2g[(size_t)r0.x * NC + lane];
      float g1 = (float)O2g[(size_t)r1.x * NC + lane];
      float g2 = (float)O2g[(size_t)r2.x * NC + lane];
      float g3 = (float)O2g[(size_t)r3.x * NC + lane];
      o2 = fmaf(__int_as_float(r0.y), g0, o2);
      o2 = fmaf(__int_as_float(r1.y), g1, o2);
      o2 = fmaf(__int_as_float(r2.y), g2, o2);
      o2 = fmaf(__int_as_float(r3.y), g3, o2);
    }
    for (; j2 < E2; ++j2)
      o2 = fmaf(__int_as_float(e2[j2].y), (float)O2g[(size_t)e2[j2].x * NC + lane], o2);
    o1 += b2[lane];
    o2 += b4[lane];
    cat[wid][lane] = o1;
    cat[wid][NC + lane] = o2;
  }
  __syncthreads();
  float g = 0.f;
  if (lane < NC) {
    for (int k = 0; k < 2 * NC; k++)
      g = fmaf(cat[wid][k], Wls[k * NC + lane], g);
    g = 1.f / (1.f + __expf(-(g + bl[lane])));
  }
  float val = (lane < NC) ? (g * o1 + (1.f - g) * o2) : -INFINITY;
  float m = val;
#pragma unroll
  for (int off = 32; off > 0; off >>= 1) m = fmaxf(m, __shfl_xor(m, off));
  float ex = (lane < NC) ? __expf(val - m) : 0.f;
  float s = ex;
#pragma unroll
  for (int off = 32; off > 0; off >>= 1) s += __shfl_xor(s, off);
  if (lane < NC) out[(size_t)d * NC + lane] = val - m - __logf(s);
}

// ---------------- host ----------------
extern "C" void kernel_launch(void* const* d_in, const int* in_sizes, int n_in,
                              void* d_out, int out_size, void* d_ws, size_t ws_size,
                              hipStream_t stream) {
  const float* x   = (const float*)d_in[0];
  const int*   ei1 = (const int*)d_in[1];
  const float* ev1 = (const float*)d_in[2];
  const int*   ei2 = (const int*)d_in[3];
  const float* ev2 = (const float*)d_in[4];
  const float* W1  = (const float*)d_in[5];
  const float* b1  = (const float*)d_in[6];
  const float* W2  = (const float*)d_in[7];
  const float* b2  = (const float*)d_in[8];
  const float* W3  = (const float*)d_in[9];
  const float* b3  = (const float*)d_in[10];
  const float* W4  = (const float*)d_in[11];
  const float* b4  = (const float*)d_in[12];
  const float* Wl  = (const float*)d_in[13];
  const float* bl  = (const float*)d_in[14];
  float* out = (float*)d_out;
  char* ws = (char*)d_ws;

  int*    deg  = (int*)(ws + O_DEG);
  int*    cur  = (int*)(ws + O_CUR);       // cur_all, stride PADN
  int*    part = (int*)(ws + O_PART);
  int*    rp   = (int*)(ws + O_RP);        // rp_all, stride PADN
  int2*   e1   = (int2*)(ws + O_E1);
  int2*   e2   = (int2*)(ws + O_E2);
  __bf16* Wbt  = (__bf16*)(ws + O_WBT);
  __bf16* XWb  = (__bf16*)(ws + O_XW);
  __bf16* h1   = (__bf16*)(ws + O_H1);
  __bf16* h2   = (__bf16*)(ws + O_H2);
  __bf16* O1   = (__bf16*)(ws + O_O1);
  __bf16* O2   = (__bf16*)(ws + O_O2);

  const int* src1 = ei1;
  const int* dst1 = ei1 + NE;
  const int* src2 = ei2;
  const int* dst2 = ei2 + NE;

  hipMemsetAsync(ws + O_DEG, 0, (size_t)4 * PADN * 4, stream);

  dim3 bs(256);
  k_degree<<<dim3((NE + 255) / 256), bs, 0, stream>>>(dst1, dst2, deg);
  k_chunk_sum<<<dim3(2 * NCHUNK), bs, 0, stream>>>(deg, part);
  k_scan_part<<<dim3(1), dim3(512), 0, stream>>>(part);
  k_chunk_scan<<<dim3(2 * NCHUNK), bs, 0, stream>>>(deg, part, rp);
  k_scatter2<<<dim3((NE + 255) / 256, 2), bs, 0, stream>>>(src1, dst1, ev1,
                                                           src2, dst2, ev2,
                                                           rp, cur, e1, e2);

  k_wcvt<<<dim3(512), bs, 0, stream>>>(W1, W3, Wbt);
  k_gemm1<<<dim3(MPAD / 128), dim3(512), 0, stream>>>(x, Wbt, XWb);
  k_spmm_h<<<dim3(NN / 8, 2), bs, 0, stream>>>(XWb, rp, e1, e2, b1, b3, h1, h2);
  k_gemm2<<<dim3((NN + G2R - 1) / G2R, 2), bs, 0, stream>>>(h1, h2, W2, W4, O1, O2);
  k_out<<<dim3(NN / 4), bs, 0, stream>>>(O1, O2, rp, e1, e2, b2, b4, Wl, bl, out);
}